// Round 4
// baseline (134.178 us; speedup 1.0000x reference)
//
#include <hip/hip_runtime.h>
#include <hip/hip_bf16.h>

// Problem constants: bs=8, Na=128, Nc=256, CS=3, D=H=64, Z=8, NT=3, NET=9
// Output 0: logpi (8,256,8,8,8) f32 = 1048576 elems
// Output 1: z meshgrid (8,8,8,3) -> 1536 elems (float values)
//
// Single fused kernel: one 192-thread block per clique.
//   wave w (0..2): node MLP for clique slot w, then edge MLP for pair w
//                  (pairs: 0->(0,1), 1->(0,2), 2->(1,2))
//   barrier; wave 0 assembles logpi, wave 1 writes the z-meshgrid tail.
// Node factors are recomputed per clique (~6x redundancy) — cheaper than a
// separate launch + workspace round-trip given the tiny absolute FLOP count.

#define BS   8
#define NA   128
#define NC   256
#define DIM  64
#define ZZ   8

__global__ __launch_bounds__(192) void clique_fused_all(
    const int* __restrict__ nt, const int* __restrict__ cni,
    const float* __restrict__ node_enc, const float* __restrict__ edge_enc,
    const float* __restrict__ nW0, const float* __restrict__ nb0,
    const float* __restrict__ nW1, const float* __restrict__ nb1,
    const float* __restrict__ nW2, const float* __restrict__ nb2,
    const float* __restrict__ eW0, const float* __restrict__ eb0,
    const float* __restrict__ eW1, const float* __restrict__ eb1,
    const float* __restrict__ eW2, const float* __restrict__ eb2,
    float* __restrict__ out) {
  const int blk  = blockIdx.x;     // b*NC + c
  const int tid  = threadIdx.x;
  const int wave = tid >> 6, lane = tid & 63;
  const int b = blk >> 8;

  __shared__ int   idxs[3];
  __shared__ float nfs[3][ZZ];
  __shared__ float ef[3][DIM];

  if (tid < 3) {
    int v = cni[blk * 3 + tid];
    idxs[tid] = (v < 0 || v >= NA) ? NA : v;
  }
  __syncthreads();

  // ---- node factor for slot `wave` (written only by wave `wave`) ----
  {
    const int v = idxs[wave];
    if (v >= NA) {
      if (lane < ZZ) nfs[wave][lane] = 0.f;
    } else {
      const int t = nt[b * NA + v];
      float e = node_enc[(b * NA + v) * DIM + lane];

      float acc = nb0[t * DIM + lane];
      {
        const float* w = nW0 + t * DIM * DIM + lane;
#pragma unroll
        for (int k = 0; k < DIM; ++k) acc = fmaf(__shfl(e, k), w[k * DIM], acc);
      }
      e = fmaxf(acc, 0.f);

      acc = nb1[t * DIM + lane];
      {
        const float* w = nW1 + t * DIM * DIM + lane;
#pragma unroll
        for (int k = 0; k < DIM; ++k) acc = fmaf(__shfl(e, k), w[k * DIM], acc);
      }
      e = fmaxf(acc, 0.f);

      // layer 2: 8 outputs, split-K x8 across the wave + butterfly reduce
      const int z = lane & 7, s = lane >> 3;
      acc = 0.f;
      {
        const float* w2 = nW2 + t * DIM * ZZ + z;
#pragma unroll
        for (int k = 0; k < 8; ++k)
          acc = fmaf(__shfl(e, s * 8 + k), w2[(s * 8 + k) * ZZ], acc);
      }
      acc += __shfl_xor(acc, 8);
      acc += __shfl_xor(acc, 16);
      acc += __shfl_xor(acc, 32);
      if (lane < ZZ) nfs[wave][lane] = acc + nb2[t * ZZ + lane];
    }
  }

  // ---- edge MLP for pair `wave` (written only by wave `wave`) ----
  {
    const int p  = wave;
    const int pi = (p == 2) ? 1 : 0;
    const int pj = (p == 0) ? 1 : 2;
    const int ia = idxs[pi], jb = idxs[pj];
    if (ia >= NA || jb >= NA) {               // wave-uniform
      ef[p][lane] = 0.f;
    } else {
      const int t = nt[b * NA + jb] * 3 + nt[b * NA + ia];
      float e = edge_enc[((b * NA + ia) * NA + jb) * DIM + lane];

      float acc = eb0[t * DIM + lane];
      {
        const float* w = eW0 + t * DIM * DIM + lane;
#pragma unroll
        for (int k = 0; k < DIM; ++k) acc = fmaf(__shfl(e, k), w[k * DIM], acc);
      }
      e = fmaxf(acc, 0.f);

      acc = eb1[t * DIM + lane];
      {
        const float* w = eW1 + t * DIM * DIM + lane;
#pragma unroll
        for (int k = 0; k < DIM; ++k) acc = fmaf(__shfl(e, k), w[k * DIM], acc);
      }
      e = fmaxf(acc, 0.f);

      acc = eb2[t * DIM + lane];
      {
        const float* w = eW2 + t * DIM * DIM + lane;
#pragma unroll
        for (int k = 0; k < DIM; ++k) acc = fmaf(__shfl(e, k), w[k * DIM], acc);
      }
      ef[p][lane] = acc;
    }
  }
  __syncthreads();

  if (wave == 0) {
    // lane = z1*8+z2, loop over z0 (8 coalesced 256B stores)
    const int z1 = lane >> 3, z2 = lane & 7;
    const float base = nfs[1][z1] + nfs[2][z2] + ef[2][z1 * ZZ + z2];
    float* o = out + blk * (ZZ * ZZ * ZZ);
#pragma unroll
    for (int z0 = 0; z0 < ZZ; ++z0) {
      o[z0 * 64 + lane] = base + nfs[0][z0] + ef[0][z0 * ZZ + z1] + ef[1][z0 * ZZ + z2];
    }
  } else if (wave == 1 && blk < 24) {
    // z meshgrid tail: 1536 elems = 24 blocks * 64 lanes
    const int i = blk * 64 + lane;
    const int k = i % 3;
    const int r = i / 3;               // z0*64 + z1*8 + z2
    const int zz2 = r & 7, zz1 = (r >> 3) & 7, zz0 = r >> 6;
    const int v = (k == 0) ? zz0 : ((k == 1) ? zz1 : zz2);
    out[BS * NC * ZZ * ZZ * ZZ + i] = (float)v;
  }
}

extern "C" void kernel_launch(void* const* d_in, const int* in_sizes, int n_in,
                              void* d_out, int out_size, void* d_ws, size_t ws_size,
                              hipStream_t stream) {
  const int*   node_types = (const int*)  d_in[0];
  const float* node_enc   = (const float*)d_in[1];
  const float* edge_enc   = (const float*)d_in[2];
  const int*   cni        = (const int*)  d_in[4];
  const float* nW0 = (const float*)d_in[6];
  const float* nb0 = (const float*)d_in[7];
  const float* nW1 = (const float*)d_in[8];
  const float* nb1 = (const float*)d_in[9];
  const float* nW2 = (const float*)d_in[10];
  const float* nb2 = (const float*)d_in[11];
  const float* eW0 = (const float*)d_in[12];
  const float* eb0 = (const float*)d_in[13];
  const float* eW1 = (const float*)d_in[14];
  const float* eb1 = (const float*)d_in[15];
  const float* eW2 = (const float*)d_in[16];
  const float* eb2 = (const float*)d_in[17];

  float* out = (float*)d_out;

  clique_fused_all<<<BS * NC, 192, 0, stream>>>(
      node_types, cni, node_enc, edge_enc,
      nW0, nb0, nW1, nb1, nW2, nb2,
      eW0, eb0, eW1, eb1, eW2, eb2, out);
}

// Round 5
// 130.611 us; speedup vs baseline: 1.0273x; 1.0273x over previous
//
#include <hip/hip_runtime.h>
#include <hip/hip_bf16.h>

// Problem constants: bs=8, Na=128, Nc=256, CS=3, D=H=64, Z=8, NT=3, NET=9
// Output 0: logpi (8,256,8,8,8) f32 = 1048576 elems
// Output 1: z meshgrid (8,8,8,3) -> 1536 elems (float values)
//
// Structure (best measured, R2/R3 band):
//   prep:   convert all MLP weights f32 -> bf16 into ws (halves L2 weight
//           streaming, the dominant cost we own: 302 MB -> 151 MB)
//   node:   one wave per (b,n), shfl-matvec, fp32 acts/accum, bf16 weights
//   clique: one 256-thr block per clique; waves 0-2 edge MLPs, wave 3 node
//           gather; wave 0 assembles, wave 1 writes z tail.

#define BS   8
#define NA   128
#define NC   256
#define DIM  64
#define ZZ   8

// bf16 weight layout in ws (element offsets, 2 B each)
#define NW0B 0
#define NW1B 12288
#define NW2B 24576
#define EW0B 26112
#define EW1B 62976
#define EW2B 99840
#define WTOT 136704
// node_factor f32 buffer after weights: byte offset 273408 (4B aligned)
#define NF_BYTE_OFF 273408

// ---------------------------------------------------------------------------
// Prep: f32 -> bf16 weight conversion (runs every launch; same work per call)
// ---------------------------------------------------------------------------
__global__ __launch_bounds__(256) void prep_weights(
    const float* __restrict__ nW0, const float* __restrict__ nW1,
    const float* __restrict__ nW2, const float* __restrict__ eW0,
    const float* __restrict__ eW1, const float* __restrict__ eW2,
    __hip_bfloat16* __restrict__ wb) {
  const int i = blockIdx.x * 256 + threadIdx.x;
  const float* src;
  int off;
  if      (i < NW1B)  { src = nW0; off = NW0B; }
  else if (i < NW2B)  { src = nW1; off = NW1B; }
  else if (i < EW0B)  { src = nW2; off = NW2B; }
  else if (i < EW1B)  { src = eW0; off = EW0B; }
  else if (i < EW2B)  { src = eW1; off = EW1B; }
  else if (i < WTOT)  { src = eW2; off = EW2B; }
  else return;
  wb[i] = __float2bfloat16(src[i - off]);
}

// ---------------------------------------------------------------------------
// Node MLP: one wave per (b,n); shfl broadcast, bf16 weights, fp32 accum.
// ---------------------------------------------------------------------------
__global__ __launch_bounds__(64) void node_mlp_kernel(
    const int* __restrict__ nt, const float* __restrict__ enc,
    const __hip_bfloat16* __restrict__ wb,
    const float* __restrict__ b0, const float* __restrict__ b1,
    const float* __restrict__ b2, float* __restrict__ nf) {
  const int blk  = blockIdx.x;      // b*NA + n
  const int lane = threadIdx.x;
  const int t = nt[blk];

  float e = enc[blk * DIM + lane];

  float acc = b0[t * DIM + lane];
  {
    const __hip_bfloat16* w = wb + NW0B + t * DIM * DIM + lane;
#pragma unroll
    for (int k = 0; k < DIM; ++k)
      acc = fmaf(__shfl(e, k), __bfloat162float(w[k * DIM]), acc);
  }
  float h = fmaxf(acc, 0.f);

  acc = b1[t * DIM + lane];
  {
    const __hip_bfloat16* w = wb + NW1B + t * DIM * DIM + lane;
#pragma unroll
    for (int k = 0; k < DIM; ++k)
      acc = fmaf(__shfl(h, k), __bfloat162float(w[k * DIM]), acc);
  }
  float h1 = fmaxf(acc, 0.f);

  // layer 2: 8 outputs, split-K x8 + butterfly reduce
  const int z = lane & 7, s = lane >> 3;
  acc = 0.f;
  {
    const __hip_bfloat16* w2 = wb + NW2B + t * DIM * ZZ + z;
#pragma unroll
    for (int k = 0; k < 8; ++k)
      acc = fmaf(__shfl(h1, s * 8 + k),
                 __bfloat162float(w2[(s * 8 + k) * ZZ]), acc);
  }
  acc += __shfl_xor(acc, 8);
  acc += __shfl_xor(acc, 16);
  acc += __shfl_xor(acc, 32);
  if (lane < ZZ) nf[blk * ZZ + lane] = acc + b2[t * ZZ + lane];
}

// ---------------------------------------------------------------------------
// Fused clique kernel: one 256-thread block per clique.
// ---------------------------------------------------------------------------
__global__ __launch_bounds__(256) void clique_fused_kernel(
    const int* __restrict__ nt, const int* __restrict__ cni,
    const float* __restrict__ edge_enc, const float* __restrict__ nf,
    const __hip_bfloat16* __restrict__ wb,
    const float* __restrict__ eb0, const float* __restrict__ eb1,
    const float* __restrict__ eb2, float* __restrict__ out) {
  const int blk  = blockIdx.x;     // b*NC + c
  const int tid  = threadIdx.x;
  const int wave = tid >> 6, lane = tid & 63;
  const int b = blk >> 8;

  __shared__ int   idxs[3];
  __shared__ float nfs[3][ZZ];
  __shared__ float ef[3][DIM];

  if (tid < 3) {
    int v = cni[blk * 3 + tid];
    idxs[tid] = (v < 0 || v >= NA) ? NA : v;
  }
  __syncthreads();

  if (wave == 3) {
    if (lane < 3 * ZZ) {
      const int i = lane >> 3, z = lane & 7, v = idxs[i];
      nfs[i][z] = (v < NA) ? nf[(b * NA + v) * ZZ + z] : 0.f;
    }
  } else {
    const int p  = wave;                      // pair index
    const int pi = (p == 2) ? 1 : 0;
    const int pj = (p == 0) ? 1 : 2;
    const int ia = idxs[pi], jb = idxs[pj];
    if (ia >= NA || jb >= NA) {               // wave-uniform
      ef[p][lane] = 0.f;
    } else {
      const int t = nt[b * NA + jb] * 3 + nt[b * NA + ia];
      float e = edge_enc[((b * NA + ia) * NA + jb) * DIM + lane];

      float acc = eb0[t * DIM + lane];
      {
        const __hip_bfloat16* w = wb + EW0B + t * DIM * DIM + lane;
#pragma unroll
        for (int k = 0; k < DIM; ++k)
          acc = fmaf(__shfl(e, k), __bfloat162float(w[k * DIM]), acc);
      }
      e = fmaxf(acc, 0.f);

      acc = eb1[t * DIM + lane];
      {
        const __hip_bfloat16* w = wb + EW1B + t * DIM * DIM + lane;
#pragma unroll
        for (int k = 0; k < DIM; ++k)
          acc = fmaf(__shfl(e, k), __bfloat162float(w[k * DIM]), acc);
      }
      e = fmaxf(acc, 0.f);

      acc = eb2[t * DIM + lane];
      {
        const __hip_bfloat16* w = wb + EW2B + t * DIM * DIM + lane;
#pragma unroll
        for (int k = 0; k < DIM; ++k)
          acc = fmaf(__shfl(e, k), __bfloat162float(w[k * DIM]), acc);
      }
      ef[p][lane] = acc;
    }
  }
  __syncthreads();

  if (wave == 0) {
    const int z1 = lane >> 3, z2 = lane & 7;
    const float base = nfs[1][z1] + nfs[2][z2] + ef[2][z1 * ZZ + z2];
    float* o = out + blk * (ZZ * ZZ * ZZ);
#pragma unroll
    for (int z0 = 0; z0 < ZZ; ++z0) {
      o[z0 * 64 + lane] = base + nfs[0][z0] + ef[0][z0 * ZZ + z1] + ef[1][z0 * ZZ + z2];
    }
  } else if (wave == 1 && blk < 24) {
    // z meshgrid tail: 1536 elems = 24 blocks * 64 lanes
    const int i = blk * 64 + lane;
    const int k = i % 3;
    const int r = i / 3;               // z0*64 + z1*8 + z2
    const int zz2 = r & 7, zz1 = (r >> 3) & 7, zz0 = r >> 6;
    const int v = (k == 0) ? zz0 : ((k == 1) ? zz1 : zz2);
    out[BS * NC * ZZ * ZZ * ZZ + i] = (float)v;
  }
}

extern "C" void kernel_launch(void* const* d_in, const int* in_sizes, int n_in,
                              void* d_out, int out_size, void* d_ws, size_t ws_size,
                              hipStream_t stream) {
  const int*   node_types = (const int*)  d_in[0];
  const float* node_enc   = (const float*)d_in[1];
  const float* edge_enc   = (const float*)d_in[2];
  const int*   cni        = (const int*)  d_in[4];
  const float* nW0 = (const float*)d_in[6];
  const float* nb0 = (const float*)d_in[7];
  const float* nW1 = (const float*)d_in[8];
  const float* nb1 = (const float*)d_in[9];
  const float* nW2 = (const float*)d_in[10];
  const float* nb2 = (const float*)d_in[11];
  const float* eW0 = (const float*)d_in[12];
  const float* eb0 = (const float*)d_in[13];
  const float* eW1 = (const float*)d_in[14];
  const float* eb1 = (const float*)d_in[15];
  const float* eW2 = (const float*)d_in[16];
  const float* eb2 = (const float*)d_in[17];

  float* out = (float*)d_out;
  __hip_bfloat16* wb = (__hip_bfloat16*)d_ws;
  float* node_factor = (float*)((char*)d_ws + NF_BYTE_OFF);

  prep_weights<<<(WTOT + 255) / 256, 256, 0, stream>>>(
      nW0, nW1, nW2, eW0, eW1, eW2, wb);

  node_mlp_kernel<<<BS * NA, 64, 0, stream>>>(
      node_types, node_enc, wb, nb0, nb1, nb2, node_factor);

  clique_fused_kernel<<<BS * NC, 256, 0, stream>>>(
      node_types, cni, edge_enc, node_factor, wb, eb0, eb1, eb2, out);
}

// Round 6
// 125.878 us; speedup vs baseline: 1.0659x; 1.0376x over previous
//
#include <hip/hip_runtime.h>
#include <hip/hip_bf16.h>

// Problem constants: bs=8, Na=128, Nc=256, CS=3, D=H=64, Z=8, NT=3, NET=9
// Output 0: logpi (8,256,8,8,8) f32 = 1048576 elems
// Output 1: z meshgrid (8,8,8,3) -> 1536 elems (float values)
//
// Best-measured structure (R2, 125.6 us): fp32 weights (bf16 regressed:
// extra prep launch + 2B scalar weight loads beat the saved L2 bytes).
//   A: node MLP, 256-thr split-K x4 block per (b,n)
//   B: edge MLP, 256-thr split-K x4 block per (clique, pair) -> ws
//   C: assemble, 1 wave per clique (+ z meshgrid tail)

#define BS   8
#define NA   128
#define NC   256
#define DIM  64
#define ZZ   8

// ws layout: [0, 32KB)  node_factor (8*128*8 f32)
//            [32KB, +1.5MB) ef buffer (6144 pairs * 64 f32)
#define WS_EF_OFF (BS * NA * ZZ)

// ---------------------------------------------------------------------------
// Kernel A: node MLP, one block (256 thr, split-K x4) per (b,n).
// ---------------------------------------------------------------------------
__global__ __launch_bounds__(256) void node_mlp_kernel(
    const int* __restrict__ nt, const float* __restrict__ enc,
    const float* __restrict__ W0, const float* __restrict__ b0,
    const float* __restrict__ W1, const float* __restrict__ b1,
    const float* __restrict__ W2, const float* __restrict__ b2,
    float* __restrict__ nf) {
  const int blk = blockIdx.x;          // b*NA + n
  const int tid = threadIdx.x;
  const int j = tid & 63, s = tid >> 6;  // wave s handles K-slice s
  const int t = nt[blk];

  __shared__ float e[DIM];
  __shared__ float h[DIM];
  __shared__ float red[4][DIM];
  __shared__ float red2[8][ZZ];

  if (tid < DIM) e[tid] = enc[blk * DIM + tid];
  __syncthreads();

  // layer 0: e -> h (relu)
  {
    float a = 0.f;
    const float* w = W0 + t * DIM * DIM + s * 16 * DIM + j;
#pragma unroll
    for (int k = 0; k < 16; ++k) a = fmaf(e[s * 16 + k], w[k * DIM], a);
    red[s][j] = a;
  }
  __syncthreads();
  if (s == 0) {
    float v = red[0][j] + red[1][j] + red[2][j] + red[3][j] + b0[t * DIM + j];
    h[j] = fmaxf(v, 0.f);
  }
  __syncthreads();

  // layer 1: h -> e (relu)
  {
    float a = 0.f;
    const float* w = W1 + t * DIM * DIM + s * 16 * DIM + j;
#pragma unroll
    for (int k = 0; k < 16; ++k) a = fmaf(h[s * 16 + k], w[k * DIM], a);
    red[s][j] = a;
  }
  __syncthreads();
  if (s == 0) {
    float v = red[0][j] + red[1][j] + red[2][j] + red[3][j] + b1[t * DIM + j];
    e[j] = fmaxf(v, 0.f);
  }
  __syncthreads();

  // layer 2: e (64) -> nf (8); threads 0..63, split-K x8
  if (tid < DIM) {
    const int j2 = tid & 7, s2 = tid >> 3;   // s2: 0..7
    float a = 0.f;
    const float* w = W2 + t * DIM * ZZ + s2 * 8 * ZZ + j2;
#pragma unroll
    for (int k = 0; k < 8; ++k) a = fmaf(e[s2 * 8 + k], w[k * ZZ], a);
    red2[s2][j2] = a;
  }
  __syncthreads();
  if (tid < ZZ) {
    float v = b2[t * ZZ + tid];
#pragma unroll
    for (int s2 = 0; s2 < 8; ++s2) v += red2[s2][tid];
    nf[blk * ZZ + tid] = v;
  }
}

// ---------------------------------------------------------------------------
// Kernel B: edge MLP, one block (256 thr, split-K x4) per (clique, pair).
// Writes ef[pairIdx][64] to ws.
// ---------------------------------------------------------------------------
__global__ __launch_bounds__(256) void edge_mlp_kernel(
    const int* __restrict__ nt, const int* __restrict__ cni,
    const float* __restrict__ edge_enc,
    const float* __restrict__ eW0, const float* __restrict__ eb0,
    const float* __restrict__ eW1, const float* __restrict__ eb1,
    const float* __restrict__ eW2, const float* __restrict__ eb2,
    float* __restrict__ ef_out) {
  const int blk = blockIdx.x;            // clique*3 + pair
  const int tid = threadIdx.x;
  const int j = tid & 63, s = tid >> 6;
  const int clique = blk / 3, pair = blk - clique * 3;
  const int b = clique >> 8;

  // pairs (slot_i, slot_j): (0,1),(0,2),(1,2)
  const int pi = (pair == 2) ? 1 : 0;
  const int pj = (pair == 0) ? 1 : 2;

  __shared__ int idxs[2];
  __shared__ float e[DIM];
  __shared__ float h[DIM];
  __shared__ float red[4][DIM];

  if (tid == 0) {
    int va = cni[clique * 3 + pi];
    int vb = cni[clique * 3 + pj];
    idxs[0] = (va < 0 || va >= NA) ? NA : va;
    idxs[1] = (vb < 0 || vb >= NA) ? NA : vb;
  }
  __syncthreads();
  const int ia = idxs[0], jb = idxs[1];

  if (ia >= NA || jb >= NA) {          // uniform across block
    if (tid < DIM) ef_out[blk * DIM + tid] = 0.f;
    return;
  }
  const int t = nt[b * NA + jb] * 3 + nt[b * NA + ia];

  if (tid < DIM) e[tid] = edge_enc[((b * NA + ia) * NA + jb) * DIM + tid];
  __syncthreads();

  // layer 0: e -> h (relu)
  {
    float a = 0.f;
    const float* w = eW0 + t * DIM * DIM + s * 16 * DIM + j;
#pragma unroll
    for (int k = 0; k < 16; ++k) a = fmaf(e[s * 16 + k], w[k * DIM], a);
    red[s][j] = a;
  }
  __syncthreads();
  if (s == 0) {
    float v = red[0][j] + red[1][j] + red[2][j] + red[3][j] + eb0[t * DIM + j];
    h[j] = fmaxf(v, 0.f);
  }
  __syncthreads();

  // layer 1: h -> e (relu)
  {
    float a = 0.f;
    const float* w = eW1 + t * DIM * DIM + s * 16 * DIM + j;
#pragma unroll
    for (int k = 0; k < 16; ++k) a = fmaf(h[s * 16 + k], w[k * DIM], a);
    red[s][j] = a;
  }
  __syncthreads();
  if (s == 0) {
    float v = red[0][j] + red[1][j] + red[2][j] + red[3][j] + eb1[t * DIM + j];
    e[j] = fmaxf(v, 0.f);
  }
  __syncthreads();

  // layer 2: e -> ef (no relu), store to ws
  {
    float a = 0.f;
    const float* w = eW2 + t * DIM * DIM + s * 16 * DIM + j;
#pragma unroll
    for (int k = 0; k < 16; ++k) a = fmaf(e[s * 16 + k], w[k * DIM], a);
    red[s][j] = a;
  }
  __syncthreads();
  if (s == 0) {
    ef_out[blk * DIM + j] =
        red[0][j] + red[1][j] + red[2][j] + red[3][j] + eb2[t * DIM + j];
  }
}

// ---------------------------------------------------------------------------
// Kernel C: assembly. One wave per clique; also writes the z meshgrid tail.
// ---------------------------------------------------------------------------
__global__ __launch_bounds__(64) void assemble_kernel(
    const int* __restrict__ cni, const float* __restrict__ nf,
    const float* __restrict__ ef_in, float* __restrict__ out) {
  const int blk = blockIdx.x;          // b*NC + c
  const int lane = threadIdx.x;
  const int b = blk >> 8;

  __shared__ int idxs[3];
  __shared__ float nfs[3][ZZ];
  __shared__ float ef[3][DIM];

  if (lane < 3) {
    int v = cni[blk * 3 + lane];
    idxs[lane] = (v < 0 || v >= NA) ? NA : v;
  }
  __syncthreads();
  if (lane < 3 * ZZ) {
    const int i = lane >> 3, z = lane & 7;
    const int v = idxs[i];
    nfs[i][z] = (v < NA) ? nf[(b * NA + v) * ZZ + z] : 0.f;
  }
#pragma unroll
  for (int p = 0; p < 3; ++p) ef[p][lane] = ef_in[(blk * 3 + p) * DIM + lane];
  __syncthreads();

  const int z1 = lane >> 3, z2 = lane & 7;
  const float base = nfs[1][z1] + nfs[2][z2] + ef[2][z1 * ZZ + z2];
  float* o = out + blk * (ZZ * ZZ * ZZ);
#pragma unroll
  for (int z0 = 0; z0 < ZZ; ++z0) {
    o[z0 * 64 + lane] = base + nfs[0][z0] + ef[0][z0 * ZZ + z1] + ef[1][z0 * ZZ + z2];
  }

  // z meshgrid tail: 1536 elems = 24 blocks * 64 lanes
  if (blk < 24) {
    const int i = blk * 64 + lane;
    const int k = i % 3;
    const int r = i / 3;               // z0*64 + z1*8 + z2
    const int zz2 = r & 7, zz1 = (r >> 3) & 7, zz0 = r >> 6;
    const int v = (k == 0) ? zz0 : ((k == 1) ? zz1 : zz2);
    out[BS * NC * ZZ * ZZ * ZZ + i] = (float)v;
  }
}

extern "C" void kernel_launch(void* const* d_in, const int* in_sizes, int n_in,
                              void* d_out, int out_size, void* d_ws, size_t ws_size,
                              hipStream_t stream) {
  const int*   node_types = (const int*)  d_in[0];
  const float* node_enc   = (const float*)d_in[1];
  const float* edge_enc   = (const float*)d_in[2];
  const int*   cni        = (const int*)  d_in[4];
  const float* nW0 = (const float*)d_in[6];
  const float* nb0 = (const float*)d_in[7];
  const float* nW1 = (const float*)d_in[8];
  const float* nb1 = (const float*)d_in[9];
  const float* nW2 = (const float*)d_in[10];
  const float* nb2 = (const float*)d_in[11];
  const float* eW0 = (const float*)d_in[12];
  const float* eb0 = (const float*)d_in[13];
  const float* eW1 = (const float*)d_in[14];
  const float* eb1 = (const float*)d_in[15];
  const float* eW2 = (const float*)d_in[16];
  const float* eb2 = (const float*)d_in[17];

  float* out = (float*)d_out;
  float* node_factor = (float*)d_ws;
  float* ef_buf = (float*)d_ws + WS_EF_OFF;

  node_mlp_kernel<<<BS * NA, 256, 0, stream>>>(
      node_types, node_enc, nW0, nb0, nW1, nb1, nW2, nb2, node_factor);

  edge_mlp_kernel<<<BS * NC * 3, 256, 0, stream>>>(
      node_types, cni, edge_enc, eW0, eb0, eW1, eb1, eW2, eb2, ef_buf);

  assemble_kernel<<<BS * NC, 64, 0, stream>>>(cni, node_factor, ef_buf, out);
}